// Round 11
// baseline (130.709 us; speedup 1.0000x reference)
//
#include <hip/hip_runtime.h>
#include <hip/hip_cooperative_groups.h>
#include <math.h>

namespace cg = cooperative_groups;

// x: (8,16,512,64) fp32; flat = [wk | wq], each (64,4). Output: int32 top-12 idx.
constexpr int kDIn  = 64;
constexpr int kN    = 512;
constexpr int kTopK = 12;
constexpr int kNBt  = 128;          // 8*16
constexpr int kS    = 4;            // row-slices per tile
constexpr int kRows = kN / kS;      // 128 rows per block
// exp(SCALE*h) = exp2(CEXP*h); SCALE = 0.125; CEXP = SCALE*log2(e)
#define CEXP 0.18033688f
#define EXP2(v) __builtin_amdgcn_exp2f(v)
#define LOG2F(v) __builtin_amdgcn_logf(v)       // v_log_f32 = log base 2
// NUMERIC INVARIANT (R3/R5): every exp2 argument <= 0 via an EXACT row max
// (two-pass per slice + exact merge). Terms in [0,1], l in [1,512] -- no
// denormal, no inf, immune to FTZ.

#define DOT4(k, q)        fmaf((k).x,(q).x, fmaf((k).y,(q).y, fmaf((k).z,(q).z, (k).w*(q).w)))
#define DOT4A(k, q, add)  fmaf((k).x,(q).x, fmaf((k).y,(q).y, fmaf((k).z,(q).z, fmaf((k).w,(q).w,(add)))))

// ---- workspace layout (floats) ----
constexpr size_t kOffKp = 0;                                  // Kp [128][512][4] (CEXP-scaled)
constexpr size_t kOffQp = kOffKp + (size_t)kNBt * kN * 4;     // Qp [128][512][4]
constexpr size_t kOffAp = kOffQp + (size_t)kNBt * kN * 4;     // apart [128][16][512]
constexpr size_t kWsFloats = kOffAp + (size_t)kNBt * 16 * kN;

// ============ cooperative kernel: everything in ONE launch ============
// grid 512 x 512thr, 2 blocks/CU (co-resident: 512 = 2*256 CUs).
// Phase A: block (tile,s) projects its own 128 rows (x read ONCE chip-wide).
// Phase B: register-tiled rowstats + colsum (R10's proven code).
// Phase C: blocks 0..127 do the top-12.
__global__ __launch_bounds__(512, 4) void coop_attn_kernel(
    const float* __restrict__ x, const float* __restrict__ flat,
    float* __restrict__ ws, int* __restrict__ out)
{
  __shared__ float4 Wk_[67];                   // bank-padded: idx = c + (c>>4)
  __shared__ float4 Wq_[67];
  __shared__ float4 Qs[kN];                    // unscaled Q (8 KB)
  __shared__ float4 Ks[kRows];                 // CEXP-scaled K slice (2 KB)
  __shared__ float2 Pp[16 * kRows];            // (m,l) per (j-slice,row) (16 KB)
  __shared__ __align__(16) float Cs[kRows];    // c_i = m_i + log2(l_i)

  cg::grid_group grid = cg::this_grid();

  const int tid  = threadIdx.x;
  const int b    = blockIdx.x;
  const int tile = b >> 2;
  const int s    = b & 3;

  float4* Kp4 = reinterpret_cast<float4*>(ws + kOffKp);
  float4* Qp4 = reinterpret_cast<float4*>(ws + kOffQp);
  float*  apart = ws + kOffAp;

  // ---- stage weights (bank-padded) ----
  if (tid < 64) {
    float4 a = reinterpret_cast<const float4*>(flat)[tid];        // wk row tid
    float4 bq = reinterpret_cast<const float4*>(flat)[tid + 64];  // wq row tid
    Wk_[tid + (tid >> 4)] = a;
    Wq_[tid + (tid >> 4)] = bq;
  }
  __syncthreads();

  // ---- phase A: project own 128 rows; 4 threads/row, 16-col slices ----
  {
    const int r  = tid >> 2;            // 0..127
    const int sl = tid & 3;             // c-slice [sl*16, +16)
    const int row = s * kRows + r;
    const float4* xr4 = reinterpret_cast<const float4*>(x)
                        + ((size_t)tile * kN + row) * 16 + sl * 4;
    float k0=0.f,k1=0.f,k2=0.f,k3=0.f, q0=0.f,q1=0.f,q2=0.f,q3=0.f;
#pragma unroll
    for (int it = 0; it < 4; ++it) {
      float4 xv = xr4[it];
#pragma unroll
      for (int u = 0; u < 4; ++u) {
        float v = (u==0)?xv.x:(u==1)?xv.y:(u==2)?xv.z:xv.w;
        float4 a  = Wk_[sl*17 + it*4 + u];   // c = sl*16+it*4+u; idx = c + (c>>4)
        float4 bq = Wq_[sl*17 + it*4 + u];
        k0 = fmaf(v, a.x, k0);  k1 = fmaf(v, a.y, k1);
        k2 = fmaf(v, a.z, k2);  k3 = fmaf(v, a.w, k3);
        q0 = fmaf(v, bq.x, q0); q1 = fmaf(v, bq.y, q1);
        q2 = fmaf(v, bq.z, q2); q3 = fmaf(v, bq.w, q3);
      }
    }
    // reduce over the 4 lanes of the quad (lanes 4r..4r+3, same wave)
#pragma unroll
    for (int off = 1; off <= 2; off <<= 1) {
      k0 += __shfl_xor(k0, off); k1 += __shfl_xor(k1, off);
      k2 += __shfl_xor(k2, off); k3 += __shfl_xor(k3, off);
      q0 += __shfl_xor(q0, off); q1 += __shfl_xor(q1, off);
      q2 += __shfl_xor(q2, off); q3 += __shfl_xor(q3, off);
    }
    if (sl == 0) {
      Kp4[(size_t)tile * kN + row] = make_float4(CEXP*k0, CEXP*k1, CEXP*k2, CEXP*k3);
      Qp4[(size_t)tile * kN + row] = make_float4(q0, q1, q2, q3);
    }
  }
  grid.sync();

  // ---- stage Q (all 512 rows) + K slice from global (coalesced, L2-hot) ----
  Qs[tid] = Qp4[(size_t)tile * kN + tid];
  if (tid < kRows) Ks[tid] = Kp4[(size_t)tile * kN + s * kRows + tid];
  __syncthreads();

  // ---- phase B1: rowstats, register-tiled (R10 verbatim) ----
  {
    const int quad  = tid & 31;
    const int slice = tid >> 5;
    const float4 k0 = Ks[quad*4+0], k1 = Ks[quad*4+1];
    const float4 k2 = Ks[quad*4+2], k3 = Ks[quad*4+3];
    const float4* qb = &Qs[slice << 5];

    float m0=-INFINITY, m1=-INFINITY, m2=-INFINITY, m3=-INFINITY;
#pragma unroll 4
    for (int j = 0; j < 32; ++j) {
      float4 q = qb[j];
      m0 = fmaxf(m0, DOT4(k0, q));
      m1 = fmaxf(m1, DOT4(k1, q));
      m2 = fmaxf(m2, DOT4(k2, q));
      m3 = fmaxf(m3, DOT4(k3, q));
    }
    float l0=0.f, l1=0.f, l2=0.f, l3=0.f;
#pragma unroll 4
    for (int j = 0; j < 32; ++j) {
      float4 q = qb[j];
      l0 += EXP2(DOT4A(k0, q, -m0));
      l1 += EXP2(DOT4A(k1, q, -m1));
      l2 += EXP2(DOT4A(k2, q, -m2));
      l3 += EXP2(DOT4A(k3, q, -m3));
    }
    float4* pp4 = reinterpret_cast<float4*>(&Pp[slice * kRows + quad*4]);
    pp4[0] = make_float4(m0, l0, m1, l1);
    pp4[1] = make_float4(m2, l2, m3, l3);
  }
  __syncthreads();

  // ---- merge 16 j-slice partials per row (exact max, scaled sums) ----
  if (tid < kRows) {
    float m = -INFINITY;
    float2 pr[16];
#pragma unroll
    for (int sl = 0; sl < 16; ++sl) {
      pr[sl] = Pp[sl * kRows + tid];
      m = fmaxf(m, pr[sl].x);
    }
    float l = 0.f;
#pragma unroll
    for (int sl = 0; sl < 16; ++sl) l += pr[sl].y * EXP2(pr[sl].x - m);
    Cs[tid] = m + LOG2F(l);            // l in [1,512]
  }
  __syncthreads();

  // ---- phase B2: colsum, register-tiled (R10 verbatim) ----
  {
    const int cq = tid & 127;
    const int rs = tid >> 7;
    const float4 q0 = Qs[cq*4+0], q1 = Qs[cq*4+1];
    const float4 q2 = Qs[cq*4+2], q3 = Qs[cq*4+3];
    const float4* kb = &Ks[rs << 5];
    const float4* cb = reinterpret_cast<const float4*>(&Cs[rs << 5]);

    float a0=0.f, a1=0.f, a2=0.f, a3=0.f;
#pragma unroll 2
    for (int ii = 0; ii < 8; ++ii) {
      float4 cc = cb[ii];
      float4 ka = kb[ii*4+0], kb_ = kb[ii*4+1], kc = kb[ii*4+2], kd = kb[ii*4+3];
      a0 += EXP2(DOT4A(q0, ka, -cc.x));  a1 += EXP2(DOT4A(q1, ka, -cc.x));
      a2 += EXP2(DOT4A(q2, ka, -cc.x));  a3 += EXP2(DOT4A(q3, ka, -cc.x));
      a0 += EXP2(DOT4A(q0, kb_, -cc.y)); a1 += EXP2(DOT4A(q1, kb_, -cc.y));
      a2 += EXP2(DOT4A(q2, kb_, -cc.y)); a3 += EXP2(DOT4A(q3, kb_, -cc.y));
      a0 += EXP2(DOT4A(q0, kc, -cc.z));  a1 += EXP2(DOT4A(q1, kc, -cc.z));
      a2 += EXP2(DOT4A(q2, kc, -cc.z));  a3 += EXP2(DOT4A(q3, kc, -cc.z));
      a0 += EXP2(DOT4A(q0, kd, -cc.w));  a1 += EXP2(DOT4A(q1, kd, -cc.w));
      a2 += EXP2(DOT4A(q2, kd, -cc.w));  a3 += EXP2(DOT4A(q3, kd, -cc.w));
    }
    reinterpret_cast<float4*>(apart + ((size_t)(tile*4 + s) * 4 + rs) * kN)[cq] =
        make_float4(a0, a1, a2, a3);
  }
  grid.sync();

  // ---- phase C: blocks 0..127, wave 0: sum 16 partials + top-12 ----
  if (b < kNBt && tid < 64) {
    const int lane = tid;
    const float* P = apart + (size_t)b * 16 * kN;
    float v[8];
    {
      float4 acc0 = make_float4(0.f,0.f,0.f,0.f);
      float4 acc1 = make_float4(0.f,0.f,0.f,0.f);
#pragma unroll
      for (int sl = 0; sl < 16; ++sl) {
        const float4* Ps = reinterpret_cast<const float4*>(P + sl * kN);
        float4 u0 = Ps[lane*2], u1 = Ps[lane*2+1];
        acc0.x += u0.x; acc0.y += u0.y; acc0.z += u0.z; acc0.w += u0.w;
        acc1.x += u1.x; acc1.y += u1.y; acc1.z += u1.z; acc1.w += u1.w;
      }
      v[0]=acc0.x; v[1]=acc0.y; v[2]=acc0.z; v[3]=acc0.w;
      v[4]=acc1.x; v[5]=acc1.y; v[6]=acc1.z; v[7]=acc1.w;
    }
    for (int rnd = 0; rnd < kTopK; ++rnd) {
      float bv = v[0];
      int   bi = lane * 8;
#pragma unroll
      for (int r = 1; r < 8; ++r)
        if (v[r] > bv) { bv = v[r]; bi = lane * 8 + r; }
#pragma unroll
      for (int off = 32; off >= 1; off >>= 1) {
        float ov = __shfl_xor(bv, off);
        int   oi = __shfl_xor(bi, off);
        if (ov > bv || (ov == bv && oi < bi)) { bv = ov; bi = oi; }
      }
      if (lane == 0) out[b * kTopK + rnd] = bi;
#pragma unroll
      for (int r = 0; r < 8; ++r)
        if (lane * 8 + r == bi) v[r] = -INFINITY;
    }
  }
}

// ============ backup path: R10's two-kernel pipeline (proven, 40.4 us) ============
__global__ __launch_bounds__(512, 4) void fused_attn_kernel(
    const float* __restrict__ x, const float* __restrict__ flat,
    float* __restrict__ apart)
{
  __shared__ float4 Wk[kDIn];
  __shared__ float4 Wq[kDIn];
  __shared__ float4 Qs[kN];
  __shared__ float4 Ks[kRows];
  __shared__ float2 Pp[16 * kRows];
  __shared__ __align__(16) float Cs[kRows];

  const int tid  = threadIdx.x;
  const int p    = blockIdx.x;
  const int xcd  = p & 7;
  const int s    = (p >> 3) & 3;
  const int tile = ((p >> 5) << 3) | xcd;

  if (tid < 64)       Wk[tid]      = reinterpret_cast<const float4*>(flat)[tid];
  else if (tid < 128) Wq[tid - 64] = reinterpret_cast<const float4*>(flat)[tid];
  __syncthreads();

  {
    const float4* xr4 = reinterpret_cast<const float4*>(x + ((size_t)tile * kN + tid) * kDIn);
    float q0=0.f,q1=0.f,q2=0.f,q3=0.f;
    if ((tid >> 7) == s) {
      float k0=0.f,k1=0.f,k2=0.f,k3=0.f;
#pragma unroll
      for (int cc = 0; cc < kDIn / 4; ++cc) {
        float4 xv = xr4[cc];
#pragma unroll
        for (int u = 0; u < 4; ++u) {
          float v = (u==0)?xv.x:(u==1)?xv.y:(u==2)?xv.z:xv.w;
          float4 a = Wk[cc*4+u];
          float4 b = Wq[cc*4+u];
          k0 = fmaf(v, a.x, k0); k1 = fmaf(v, a.y, k1);
          k2 = fmaf(v, a.z, k2); k3 = fmaf(v, a.w, k3);
          q0 = fmaf(v, b.x, q0); q1 = fmaf(v, b.y, q1);
          q2 = fmaf(v, b.z, q2); q3 = fmaf(v, b.w, q3);
        }
      }
      Ks[tid & 127] = make_float4(CEXP*k0, CEXP*k1, CEXP*k2, CEXP*k3);
    } else {
#pragma unroll
      for (int cc = 0; cc < kDIn / 4; ++cc) {
        float4 xv = xr4[cc];
#pragma unroll
        for (int u = 0; u < 4; ++u) {
          float v = (u==0)?xv.x:(u==1)?xv.y:(u==2)?xv.z:xv.w;
          float4 b = Wq[cc*4+u];
          q0 = fmaf(v, b.x, q0); q1 = fmaf(v, b.y, q1);
          q2 = fmaf(v, b.z, q2); q3 = fmaf(v, b.w, q3);
        }
      }
    }
    Qs[tid] = make_float4(q0, q1, q2, q3);
  }
  __syncthreads();

  {
    const int quad  = tid & 31;
    const int slice = tid >> 5;
    const float4 k0 = Ks[quad*4+0], k1 = Ks[quad*4+1];
    const float4 k2 = Ks[quad*4+2], k3 = Ks[quad*4+3];
    const float4* qb = &Qs[slice << 5];

    float m0=-INFINITY, m1=-INFINITY, m2=-INFINITY, m3=-INFINITY;
#pragma unroll 4
    for (int j = 0; j < 32; ++j) {
      float4 q = qb[j];
      m0 = fmaxf(m0, DOT4(k0, q));
      m1 = fmaxf(m1, DOT4(k1, q));
      m2 = fmaxf(m2, DOT4(k2, q));
      m3 = fmaxf(m3, DOT4(k3, q));
    }
    float l0=0.f, l1=0.f, l2=0.f, l3=0.f;
#pragma unroll 4
    for (int j = 0; j < 32; ++j) {
      float4 q = qb[j];
      l0 += EXP2(DOT4A(k0, q, -m0));
      l1 += EXP2(DOT4A(k1, q, -m1));
      l2 += EXP2(DOT4A(k2, q, -m2));
      l3 += EXP2(DOT4A(k3, q, -m3));
    }
    float4* pp4 = reinterpret_cast<float4*>(&Pp[slice * kRows + quad*4]);
    pp4[0] = make_float4(m0, l0, m1, l1);
    pp4[1] = make_float4(m2, l2, m3, l3);
  }
  __syncthreads();

  if (tid < kRows) {
    float m = -INFINITY;
    float2 pr[16];
#pragma unroll
    for (int sl = 0; sl < 16; ++sl) {
      pr[sl] = Pp[sl * kRows + tid];
      m = fmaxf(m, pr[sl].x);
    }
    float l = 0.f;
#pragma unroll
    for (int sl = 0; sl < 16; ++sl) l += pr[sl].y * EXP2(pr[sl].x - m);
    Cs[tid] = m + LOG2F(l);
  }
  __syncthreads();

  {
    const int cq = tid & 127;
    const int rs = tid >> 7;
    const float4 q0 = Qs[cq*4+0], q1 = Qs[cq*4+1];
    const float4 q2 = Qs[cq*4+2], q3 = Qs[cq*4+3];
    const float4* kb = &Ks[rs << 5];
    const float4* cb = reinterpret_cast<const float4*>(&Cs[rs << 5]);

    float a0=0.f, a1=0.f, a2=0.f, a3=0.f;
#pragma unroll 2
    for (int ii = 0; ii < 8; ++ii) {
      float4 cc = cb[ii];
      float4 ka = kb[ii*4+0], kb_ = kb[ii*4+1], kc = kb[ii*4+2], kd = kb[ii*4+3];
      a0 += EXP2(DOT4A(q0, ka, -cc.x));  a1 += EXP2(DOT4A(q1, ka, -cc.x));
      a2 += EXP2(DOT4A(q2, ka, -cc.x));  a3 += EXP2(DOT4A(q3, ka, -cc.x));
      a0 += EXP2(DOT4A(q0, kb_, -cc.y)); a1 += EXP2(DOT4A(q1, kb_, -cc.y));
      a2 += EXP2(DOT4A(q2, kb_, -cc.y)); a3 += EXP2(DOT4A(q3, kb_, -cc.y));
      a0 += EXP2(DOT4A(q0, kc, -cc.z));  a1 += EXP2(DOT4A(q1, kc, -cc.z));
      a2 += EXP2(DOT4A(q2, kc, -cc.z));  a3 += EXP2(DOT4A(q3, kc, -cc.z));
      a0 += EXP2(DOT4A(q0, kd, -cc.w));  a1 += EXP2(DOT4A(q1, kd, -cc.w));
      a2 += EXP2(DOT4A(q2, kd, -cc.w));  a3 += EXP2(DOT4A(q3, kd, -cc.w));
    }
    reinterpret_cast<float4*>(apart + ((size_t)(tile*4 + s) * 4 + rs) * kN)[cq] =
        make_float4(a0, a1, a2, a3);
  }
}

__global__ __launch_bounds__(64) void topk_kernel(
    const float* __restrict__ apart, int* __restrict__ out)
{
  const int lane = threadIdx.x;
  const int bt   = blockIdx.x;
  const float* P = apart + (size_t)bt * 16 * kN;

  float v[8];
  {
    float4 acc0 = make_float4(0.f,0.f,0.f,0.f);
    float4 acc1 = make_float4(0.f,0.f,0.f,0.f);
#pragma unroll
    for (int sl = 0; sl < 16; ++sl) {
      const float4* Ps = reinterpret_cast<const float4*>(P + sl * kN);
      float4 u0 = Ps[lane*2], u1 = Ps[lane*2+1];
      acc0.x += u0.x; acc0.y += u0.y; acc0.z += u0.z; acc0.w += u0.w;
      acc1.x += u1.x; acc1.y += u1.y; acc1.z += u1.z; acc1.w += u1.w;
    }
    v[0]=acc0.x; v[1]=acc0.y; v[2]=acc0.z; v[3]=acc0.w;
    v[4]=acc1.x; v[5]=acc1.y; v[6]=acc1.z; v[7]=acc1.w;
  }

  for (int rnd = 0; rnd < kTopK; ++rnd) {
    float bv = v[0];
    int   bi = lane * 8;
#pragma unroll
    for (int r = 1; r < 8; ++r)
      if (v[r] > bv) { bv = v[r]; bi = lane * 8 + r; }
#pragma unroll
    for (int off = 32; off >= 1; off >>= 1) {
      float ov = __shfl_xor(bv, off);
      int   oi = __shfl_xor(bi, off);
      if (ov > bv || (ov == bv && oi < bi)) { bv = ov; bi = oi; }
    }
    if (lane == 0) out[bt * kTopK + rnd] = bi;
#pragma unroll
    for (int r = 0; r < 8; ++r)
      if (lane * 8 + r == bi) v[r] = -INFINITY;
  }
}

// ============ fallback: round-1 single kernel (unexpected shape / tiny ws) ============
__global__ __launch_bounds__(512, 1) void sparse_attn_topk_fallback(
    const float* __restrict__ x, const float* __restrict__ flat, int* __restrict__ out)
{
  __shared__ float4 wk4[kDIn];
  __shared__ float4 wq4[kDIn];
  __shared__ float4 Ks[kN];
  __shared__ float4 Qs[kN];
  __shared__ float  Ms[kN];
  __shared__ float  Rl[kN];
  __shared__ float  As[kN];

  const int tid = threadIdx.x;
  const int bt  = blockIdx.x;

  if (tid < 64)       wk4[tid]      = reinterpret_cast<const float4*>(flat)[tid];
  else if (tid < 128) wq4[tid - 64] = reinterpret_cast<const float4*>(flat)[tid];
  __syncthreads();

  const float* xr = x + ((size_t)bt * kN + tid) * kDIn;
  float k0=0.f,k1=0.f,k2=0.f,k3=0.f, q0=0.f,q1=0.f,q2=0.f,q3=0.f;
#pragma unroll
  for (int c = 0; c < kDIn; ++c) {
    float xv = xr[c];
    float4 a = wk4[c];
    float4 b = wq4[c];
    k0 = fmaf(xv, a.x, k0); k1 = fmaf(xv, a.y, k1);
    k2 = fmaf(xv, a.z, k2); k3 = fmaf(xv, a.w, k3);
    q0 = fmaf(xv, b.x, q0); q1 = fmaf(xv, b.y, q1);
    q2 = fmaf(xv, b.z, q2); q3 = fmaf(xv, b.w, q3);
  }
  Ks[tid] = make_float4(k0, k1, k2, k3);
  Qs[tid] = make_float4(q0, q1, q2, q3);
  __syncthreads();

  float m = -INFINITY;
#pragma unroll 8
  for (int j = 0; j < kN; ++j) {
    float4 qj = Qs[j];
    float h = fmaf(k0, qj.x, fmaf(k1, qj.y, fmaf(k2, qj.z, k3 * qj.w)));
    m = fmaxf(m, h);
  }
  float l = 0.f;
#pragma unroll 8
  for (int j = 0; j < kN; ++j) {
    float4 qj = Qs[j];
    float h = fmaf(k0, qj.x, fmaf(k1, qj.y, fmaf(k2, qj.z, k3 * qj.w)));
    l += exp2f(CEXP * (h - m));
  }
  Ms[tid] = m;
  Rl[tid] = 1.0f / l;
  __syncthreads();

  float acc = 0.f;
#pragma unroll 8
  for (int i = 0; i < kN; ++i) {
    float4 ki = Ks[i];
    float h = fmaf(q0, ki.x, fmaf(q1, ki.y, fmaf(q2, ki.z, q3 * ki.w)));
    acc += exp2f(CEXP * (h - Ms[i])) * Rl[i];
  }
  As[tid] = acc;
  __syncthreads();

  if (tid < 64) {
    float v[8];
#pragma unroll
    for (int r = 0; r < 8; ++r) v[r] = As[tid * 8 + r];
    for (int rnd = 0; rnd < kTopK; ++rnd) {
      float bv = v[0];
      int   bi = tid * 8;
#pragma unroll
      for (int r = 1; r < 8; ++r)
        if (v[r] > bv) { bv = v[r]; bi = tid * 8 + r; }
#pragma unroll
      for (int off = 32; off >= 1; off >>= 1) {
        float ov = __shfl_xor(bv, off);
        int   oi = __shfl_xor(bi, off);
        if (ov > bv || (ov == bv && oi < bi)) { bv = ov; bi = oi; }
      }
      if (tid == 0) out[bt * kTopK + rnd] = bi;
#pragma unroll
      for (int r = 0; r < 8; ++r)
        if (tid * 8 + r == bi) v[r] = -INFINITY;
    }
  }
}

extern "C" void kernel_launch(void* const* d_in, const int* in_sizes, int n_in,
                              void* d_out, int out_size, void* d_ws, size_t ws_size,
                              hipStream_t stream) {
  const float* x    = (const float*)d_in[0];
  const float* flat = (const float*)d_in[1];
  int* out = (int*)d_out;
  const int n_bt = in_sizes[0] / (kN * kDIn);

  if (n_bt != kNBt || ws_size < kWsFloats * sizeof(float)) {
    sparse_attn_topk_fallback<<<n_bt, kN, 0, stream>>>(x, flat, out);
    return;
  }
  float* ws = (float*)d_ws;

  // single cooperative launch (grid 512 = 2 blocks/CU, co-resident)
  void* args[] = {(void*)&x, (void*)&flat, (void*)&ws, (void*)&out};
  hipError_t err = hipLaunchCooperativeKernel(
      reinterpret_cast<void*>(coop_attn_kernel),
      dim3(kNBt * kS), dim3(kN), args, 0, stream);

  if (err != hipSuccess) {
    // backup: proven R10 two-kernel pipeline (uses apart region of ws)
    float* apart = ws + kOffAp;
    fused_attn_kernel<<<kNBt * kS, 512, 0, stream>>>(x, flat, apart);
    topk_kernel      <<<kNBt,       64, 0, stream>>>(apart, out);
  }
}

// Round 12
// 37.302 us; speedup vs baseline: 3.5041x; 3.5041x over previous
//
#include <hip/hip_runtime.h>
#include <math.h>

// x: (8,16,512,64) fp32; flat = [wk | wq], each (64,4). Output: int32 top-12 idx.
constexpr int kDIn  = 64;
constexpr int kN    = 512;
constexpr int kTopK = 12;
constexpr int kNBt  = 128;          // 8*16
constexpr int kS    = 4;            // row-slices per tile
constexpr int kRows = kN / kS;      // 128 rows per block
// exp(SCALE*h) = exp2(CEXP*h); SCALE = 0.125; CEXP = SCALE*log2(e)
#define CEXP 0.18033688f
#define EXP2(v) __builtin_amdgcn_exp2f(v)
#define LOG2F(v) __builtin_amdgcn_logf(v)       // v_log_f32 = log base 2
// NUMERIC INVARIANT (R3/R5): every exp2 argument <= 0 via an EXACT row max
// (two-pass per slice + exact merge). Terms in [0,1], l in [1,512] -- no
// denormal, no inf, immune to FTZ.
// LDS BUDGET (R9/R11 post-mortems): ds_read_b128 ~12cyc/instr/CU; weights are
// block-uniform -> scalar s_load from global (SGPR operands), NOT LDS.

#define DOT4(k, q)        fmaf((k).x,(q).x, fmaf((k).y,(q).y, fmaf((k).z,(q).z, (k).w*(q).w)))
#define DOT4A(k, q, add)  fmaf((k).x,(q).x, fmaf((k).y,(q).y, fmaf((k).z,(q).z, fmaf((k).w,(q).w,(add)))))

// ws: apart [128 tiles][16 slices][512 cols] floats = 4 MB
constexpr size_t kWsFloats = (size_t)kNBt * 16 * kN;

// ============ KA: fused projection + rowstats + colsum ============
// grid 512, block 512, 2 blocks/CU. XCD swizzle keeps 4 same-tile blocks on one
// XCD (x tile L2-resident). Phase 1 weights via uniform global loads (s_load).
__global__ __launch_bounds__(512, 4) void fused_attn_kernel(
    const float* __restrict__ x, const float* __restrict__ flat,
    float* __restrict__ apart)
{
  __shared__ float4 Qs[kN];                    // unscaled Q (8 KB)
  __shared__ float4 Ks[kRows];                 // CEXP-scaled K slice (2 KB)
  __shared__ float2 Pp[16 * kRows];            // (m,l) per (j-slice,row) (16 KB)
  __shared__ __align__(16) float Cs[kRows];    // c_i = m_i + log2(l_i)

  const int tid  = threadIdx.x;
  const int p    = blockIdx.x;
  const int xcd  = p & 7;
  const int s    = (p >> 3) & 3;
  const int tile = ((p >> 5) << 3) | xcd;

  // ---- phase 1: thread t projects row t; weights uniform -> SGPR s_loads ----
  {
    const float4* fw  = reinterpret_cast<const float4*>(flat);   // [128] uniform
    const float4* xr4 = reinterpret_cast<const float4*>(x + ((size_t)tile * kN + tid) * kDIn);
    float q0=0.f,q1=0.f,q2=0.f,q3=0.f;
    if ((tid >> 7) == s) {                     // wave-uniform branch
      float k0=0.f,k1=0.f,k2=0.f,k3=0.f;
#pragma unroll 4
      for (int cc = 0; cc < 16; ++cc) {
        float4 xv = xr4[cc];
#pragma unroll
        for (int u = 0; u < 4; ++u) {
          float v = (u==0)?xv.x:(u==1)?xv.y:(u==2)?xv.z:xv.w;
          float4 a = fw[cc*4+u];               // uniform -> s_load_dwordx4
          float4 b = fw[64 + cc*4+u];
          k0 = fmaf(v, a.x, k0); k1 = fmaf(v, a.y, k1);
          k2 = fmaf(v, a.z, k2); k3 = fmaf(v, a.w, k3);
          q0 = fmaf(v, b.x, q0); q1 = fmaf(v, b.y, q1);
          q2 = fmaf(v, b.z, q2); q3 = fmaf(v, b.w, q3);
        }
      }
      Ks[tid & 127] = make_float4(CEXP*k0, CEXP*k1, CEXP*k2, CEXP*k3);
    } else {
#pragma unroll 4
      for (int cc = 0; cc < 16; ++cc) {
        float4 xv = xr4[cc];
#pragma unroll
        for (int u = 0; u < 4; ++u) {
          float v = (u==0)?xv.x:(u==1)?xv.y:(u==2)?xv.z:xv.w;
          float4 b = fw[64 + cc*4+u];          // uniform -> s_load_dwordx4
          q0 = fmaf(v, b.x, q0); q1 = fmaf(v, b.y, q1);
          q2 = fmaf(v, b.z, q2); q3 = fmaf(v, b.w, q3);
        }
      }
    }
    Qs[tid] = make_float4(q0, q1, q2, q3);
  }
  __syncthreads();

  // ---- phase 2: rowstats, register-tiled (R10 proven) ----
  // thread = (row-quad = tid&31, j-slice = tid>>5); each Qs read feeds 4 dots.
  {
    const int quad  = tid & 31;
    const int slice = tid >> 5;
    const float4 k0 = Ks[quad*4+0], k1 = Ks[quad*4+1];
    const float4 k2 = Ks[quad*4+2], k3 = Ks[quad*4+3];
    const float4* qb = &Qs[slice << 5];

    float m0=-INFINITY, m1=-INFINITY, m2=-INFINITY, m3=-INFINITY;
#pragma unroll 4
    for (int j = 0; j < 32; ++j) {
      float4 q = qb[j];
      m0 = fmaxf(m0, DOT4(k0, q));
      m1 = fmaxf(m1, DOT4(k1, q));
      m2 = fmaxf(m2, DOT4(k2, q));
      m3 = fmaxf(m3, DOT4(k3, q));
    }
    float l0=0.f, l1=0.f, l2=0.f, l3=0.f;
#pragma unroll 4
    for (int j = 0; j < 32; ++j) {
      float4 q = qb[j];
      l0 += EXP2(DOT4A(k0, q, -m0));
      l1 += EXP2(DOT4A(k1, q, -m1));
      l2 += EXP2(DOT4A(k2, q, -m2));
      l3 += EXP2(DOT4A(k3, q, -m3));
    }
    float4* pp4 = reinterpret_cast<float4*>(&Pp[slice * kRows + quad*4]);
    pp4[0] = make_float4(m0, l0, m1, l1);
    pp4[1] = make_float4(m2, l2, m3, l3);
  }
  __syncthreads();

  // ---- merge 16 j-slice partials per row (exact max, scaled sums) ----
  if (tid < kRows) {
    float m = -INFINITY;
    float2 pr[16];
#pragma unroll
    for (int sl = 0; sl < 16; ++sl) {
      pr[sl] = Pp[sl * kRows + tid];
      m = fmaxf(m, pr[sl].x);
    }
    float l = 0.f;
#pragma unroll
    for (int sl = 0; sl < 16; ++sl) l += pr[sl].y * EXP2(pr[sl].x - m);
    Cs[tid] = m + LOG2F(l);            // l in [1,512]
  }
  __syncthreads();

  // ---- phase 3: colsum, register-tiled (R10 proven) ----
  {
    const int cq = tid & 127;
    const int rs = tid >> 7;
    const float4 q0 = Qs[cq*4+0], q1 = Qs[cq*4+1];
    const float4 q2 = Qs[cq*4+2], q3 = Qs[cq*4+3];
    const float4* kb = &Ks[rs << 5];
    const float4* cb = reinterpret_cast<const float4*>(&Cs[rs << 5]);

    float a0=0.f, a1=0.f, a2=0.f, a3=0.f;
#pragma unroll 2
    for (int ii = 0; ii < 8; ++ii) {
      float4 cc = cb[ii];
      float4 ka = kb[ii*4+0], kb_ = kb[ii*4+1], kc = kb[ii*4+2], kd = kb[ii*4+3];
      a0 += EXP2(DOT4A(q0, ka, -cc.x));  a1 += EXP2(DOT4A(q1, ka, -cc.x));
      a2 += EXP2(DOT4A(q2, ka, -cc.x));  a3 += EXP2(DOT4A(q3, ka, -cc.x));
      a0 += EXP2(DOT4A(q0, kb_, -cc.y)); a1 += EXP2(DOT4A(q1, kb_, -cc.y));
      a2 += EXP2(DOT4A(q2, kb_, -cc.y)); a3 += EXP2(DOT4A(q3, kb_, -cc.y));
      a0 += EXP2(DOT4A(q0, kc, -cc.z));  a1 += EXP2(DOT4A(q1, kc, -cc.z));
      a2 += EXP2(DOT4A(q2, kc, -cc.z));  a3 += EXP2(DOT4A(q3, kc, -cc.z));
      a0 += EXP2(DOT4A(q0, kd, -cc.w));  a1 += EXP2(DOT4A(q1, kd, -cc.w));
      a2 += EXP2(DOT4A(q2, kd, -cc.w));  a3 += EXP2(DOT4A(q3, kd, -cc.w));
    }
    reinterpret_cast<float4*>(apart + ((size_t)(tile*4 + s) * 4 + rs) * kN)[cq] =
        make_float4(a0, a1, a2, a3);
  }
}

// ============ KB: sum 16 partials + top-12; grid 128, block 64 ============
__global__ __launch_bounds__(64) void topk_kernel(
    const float* __restrict__ apart, int* __restrict__ out)
{
  const int lane = threadIdx.x;
  const int bt   = blockIdx.x;
  const float* P = apart + (size_t)bt * 16 * kN;

  float v[8];
  {
    float4 acc0 = make_float4(0.f,0.f,0.f,0.f);
    float4 acc1 = make_float4(0.f,0.f,0.f,0.f);
#pragma unroll
    for (int sl = 0; sl < 16; ++sl) {
      const float4* Ps = reinterpret_cast<const float4*>(P + sl * kN);
      float4 u0 = Ps[lane*2], u1 = Ps[lane*2+1];
      acc0.x += u0.x; acc0.y += u0.y; acc0.z += u0.z; acc0.w += u0.w;
      acc1.x += u1.x; acc1.y += u1.y; acc1.z += u1.z; acc1.w += u1.w;
    }
    v[0]=acc0.x; v[1]=acc0.y; v[2]=acc0.z; v[3]=acc0.w;
    v[4]=acc1.x; v[5]=acc1.y; v[6]=acc1.z; v[7]=acc1.w;
  }

  for (int rnd = 0; rnd < kTopK; ++rnd) {
    float bv = v[0];
    int   bi = lane * 8;
#pragma unroll
    for (int r = 1; r < 8; ++r) {
      if (v[r] > bv) { bv = v[r]; bi = lane * 8 + r; }
    }
#pragma unroll
    for (int off = 32; off >= 1; off >>= 1) {
      float ov = __shfl_xor(bv, off);
      int   oi = __shfl_xor(bi, off);
      if (ov > bv || (ov == bv && oi < bi)) { bv = ov; bi = oi; }
    }
    if (lane == 0) out[bt * kTopK + rnd] = bi;
#pragma unroll
    for (int r = 0; r < 8; ++r) {
      if (lane * 8 + r == bi) v[r] = -INFINITY;
    }
  }
}

// ============ fallback: round-1 single kernel (unexpected shape / tiny ws) ============
__global__ __launch_bounds__(512, 1) void sparse_attn_topk_fallback(
    const float* __restrict__ x, const float* __restrict__ flat, int* __restrict__ out)
{
  __shared__ float4 wk4[kDIn];
  __shared__ float4 wq4[kDIn];
  __shared__ float4 Ks[kN];
  __shared__ float4 Qs[kN];
  __shared__ float  Ms[kN];
  __shared__ float  Rl[kN];
  __shared__ float  As[kN];

  const int tid = threadIdx.x;
  const int bt  = blockIdx.x;

  if (tid < 64)       wk4[tid]      = reinterpret_cast<const float4*>(flat)[tid];
  else if (tid < 128) wq4[tid - 64] = reinterpret_cast<const float4*>(flat)[tid];
  __syncthreads();

  const float* xr = x + ((size_t)bt * kN + tid) * kDIn;
  float k0=0.f,k1=0.f,k2=0.f,k3=0.f, q0=0.f,q1=0.f,q2=0.f,q3=0.f;
#pragma unroll
  for (int c = 0; c < kDIn; ++c) {
    float xv = xr[c];
    float4 a = wk4[c];
    float4 b = wq4[c];
    k0 = fmaf(xv, a.x, k0); k1 = fmaf(xv, a.y, k1);
    k2 = fmaf(xv, a.z, k2); k3 = fmaf(xv, a.w, k3);
    q0 = fmaf(xv, b.x, q0); q1 = fmaf(xv, b.y, q1);
    q2 = fmaf(xv, b.z, q2); q3 = fmaf(xv, b.w, q3);
  }
  Ks[tid] = make_float4(k0, k1, k2, k3);
  Qs[tid] = make_float4(q0, q1, q2, q3);
  __syncthreads();

  float m = -INFINITY;
#pragma unroll 8
  for (int j = 0; j < kN; ++j) {
    float4 qj = Qs[j];
    float h = fmaf(k0, qj.x, fmaf(k1, qj.y, fmaf(k2, qj.z, k3 * qj.w)));
    m = fmaxf(m, h);
  }
  float l = 0.f;
#pragma unroll 8
  for (int j = 0; j < kN; ++j) {
    float4 qj = Qs[j];
    float h = fmaf(k0, qj.x, fmaf(k1, qj.y, fmaf(k2, qj.z, k3 * qj.w)));
    l += exp2f(CEXP * (h - m));
  }
  Ms[tid] = m;
  Rl[tid] = 1.0f / l;
  __syncthreads();

  float acc = 0.f;
#pragma unroll 8
  for (int i = 0; i < kN; ++i) {
    float4 ki = Ks[i];
    float h = fmaf(q0, ki.x, fmaf(q1, ki.y, fmaf(q2, ki.z, q3 * ki.w)));
    acc += exp2f(CEXP * (h - Ms[i])) * Rl[i];
  }
  As[tid] = acc;
  __syncthreads();

  if (tid < 64) {
    float v[8];
#pragma unroll
    for (int r = 0; r < 8; ++r) v[r] = As[tid * 8 + r];
    for (int rnd = 0; rnd < kTopK; ++rnd) {
      float bv = v[0];
      int   bi = tid * 8;
#pragma unroll
      for (int r = 1; r < 8; ++r)
        if (v[r] > bv) { bv = v[r]; bi = tid * 8 + r; }
#pragma unroll
      for (int off = 32; off >= 1; off >>= 1) {
        float ov = __shfl_xor(bv, off);
        int   oi = __shfl_xor(bi, off);
        if (ov > bv || (ov == bv && oi < bi)) { bv = ov; bi = oi; }
      }
      if (tid == 0) out[bt * kTopK + rnd] = bi;
#pragma unroll
      for (int r = 0; r < 8; ++r)
        if (tid * 8 + r == bi) v[r] = -INFINITY;
    }
  }
}

extern "C" void kernel_launch(void* const* d_in, const int* in_sizes, int n_in,
                              void* d_out, int out_size, void* d_ws, size_t ws_size,
                              hipStream_t stream) {
  const float* x    = (const float*)d_in[0];
  const float* flat = (const float*)d_in[1];
  int* out = (int*)d_out;
  const int n_bt = in_sizes[0] / (kN * kDIn);

  if (n_bt != kNBt || ws_size < kWsFloats * sizeof(float)) {
    sparse_attn_topk_fallback<<<n_bt, kN, 0, stream>>>(x, flat, out);
    return;
  }
  float* apart = (float*)d_ws;
  fused_attn_kernel<<<kNBt * kS, 512, 0, stream>>>(x, flat, apart);
  topk_kernel      <<<kNBt,       64, 0, stream>>>(apart, out);
}

// Round 13
// 36.646 us; speedup vs baseline: 3.5668x; 1.0179x over previous
//
#include <hip/hip_runtime.h>
#include <math.h>

// x: (8,16,512,64) fp32; flat = [wk | wq], each (64,4). Output: int32 top-12 idx.
constexpr int kDIn  = 64;
constexpr int kN    = 512;
constexpr int kTopK = 12;
constexpr int kNBt  = 128;          // 8*16
constexpr int kS    = 4;            // row-slices per tile
constexpr int kRows = kN / kS;      // 128 rows per block
// exp(SCALE*h) = exp2(CEXP*h); SCALE = 0.125; CEXP = SCALE*log2(e)
#define CEXP 0.18033688f
#define EXP2(v) __builtin_amdgcn_exp2f(v)
#define LOG2F(v) __builtin_amdgcn_logf(v)       // v_log_f32 = log base 2
// NUMERIC INVARIANT (R3/R5): every exp2 argument <= 0. Online rowstats keeps a
// running EXACT max at chunk granularity (R8/R9-proven): rescale factor <= 1,
// slice l in [1,512]. No denormal, no inf, immune to FTZ.
// LDS BUDGET (R9/R11): ds_read_b128 ~12cyc/instr/CU; weights stay in SGPRs
// (uniform s_load), Qs/Ks reads are register-tiled (each read feeds 4 dots).

#define DOT4(k, q)        fmaf((k).x,(q).x, fmaf((k).y,(q).y, fmaf((k).z,(q).z, (k).w*(q).w)))
#define DOT4A(k, q, add)  fmaf((k).x,(q).x, fmaf((k).y,(q).y, fmaf((k).z,(q).z, fmaf((k).w,(q).w,(add)))))

// ws: apart [128 tiles][16 slices][512 cols] floats = 4 MB
constexpr size_t kWsFloats = (size_t)kNBt * 16 * kN;

// ============ KA: fused projection + online rowstats + colsum ============
// grid 512, block 512, 2 blocks/CU. XCD swizzle keeps 4 same-tile blocks on one
// XCD (x tile L2-resident).
__global__ __launch_bounds__(512, 4) void fused_attn_kernel(
    const float* __restrict__ x, const float* __restrict__ flat,
    float* __restrict__ apart)
{
  __shared__ float4 Qs[kN];                    // unscaled Q (8 KB)
  __shared__ float4 Ks[kRows];                 // CEXP-scaled K slice (2 KB)
  __shared__ float2 Pp[16 * kRows];            // (m,l) per (j-slice,row) (16 KB)
  __shared__ __align__(16) float Cs[kRows];    // c_i = m_i + log2(l_i)

  const int tid  = threadIdx.x;
  const int p    = blockIdx.x;
  const int xcd  = p & 7;
  const int s    = (p >> 3) & 3;
  const int tile = ((p >> 5) << 3) | xcd;

  // ---- phase 1: thread t projects row t. All 16 x-loads prefetched into
  // registers (latency overlap); weights via uniform s_load (SGPR operands).
  {
    const float4* fw  = reinterpret_cast<const float4*>(flat);   // [128] uniform
    const float4* xr4 = reinterpret_cast<const float4*>(x + ((size_t)tile * kN + tid) * kDIn);
    float4 xv[16];
#pragma unroll
    for (int i = 0; i < 16; ++i) xv[i] = xr4[i];   // 16 independent loads in flight

    float q0=0.f,q1=0.f,q2=0.f,q3=0.f;
    if ((tid >> 7) == s) {                     // wave-uniform branch
      float k0=0.f,k1=0.f,k2=0.f,k3=0.f;
#pragma unroll
      for (int cc = 0; cc < 16; ++cc) {
#pragma unroll
        for (int u = 0; u < 4; ++u) {
          float v = (u==0)?xv[cc].x:(u==1)?xv[cc].y:(u==2)?xv[cc].z:xv[cc].w;
          float4 a = fw[cc*4+u];               // uniform -> s_load_dwordx4
          float4 b = fw[64 + cc*4+u];
          k0 = fmaf(v, a.x, k0); k1 = fmaf(v, a.y, k1);
          k2 = fmaf(v, a.z, k2); k3 = fmaf(v, a.w, k3);
          q0 = fmaf(v, b.x, q0); q1 = fmaf(v, b.y, q1);
          q2 = fmaf(v, b.z, q2); q3 = fmaf(v, b.w, q3);
        }
      }
      Ks[tid & 127] = make_float4(CEXP*k0, CEXP*k1, CEXP*k2, CEXP*k3);
    } else {
#pragma unroll
      for (int cc = 0; cc < 16; ++cc) {
#pragma unroll
        for (int u = 0; u < 4; ++u) {
          float v = (u==0)?xv[cc].x:(u==1)?xv[cc].y:(u==2)?xv[cc].z:xv[cc].w;
          float4 b = fw[64 + cc*4+u];          // uniform -> s_load_dwordx4
          q0 = fmaf(v, b.x, q0); q1 = fmaf(v, b.y, q1);
          q2 = fmaf(v, b.z, q2); q3 = fmaf(v, b.w, q3);
        }
      }
    }
    Qs[tid] = make_float4(q0, q1, q2, q3);
  }
  __syncthreads();

  // ---- phase 2: ONLINE rowstats, register-tiled ----
  // thread = (row-quad = tid&31 -> rows quad*4..+3, j-slice = tid>>5 -> 32 j).
  // Single pass: each Qs read feeds 4 dots; running exact max per row.
  {
    const int quad  = tid & 31;
    const int slice = tid >> 5;
    const float4 k0 = Ks[quad*4+0], k1 = Ks[quad*4+1];
    const float4 k2 = Ks[quad*4+2], k3 = Ks[quad*4+3];
    const float4* qb = &Qs[slice << 5];

    float m0=-INFINITY, m1=-INFINITY, m2=-INFINITY, m3=-INFINITY;
    float l0=0.f, l1=0.f, l2=0.f, l3=0.f;
#pragma unroll
    for (int c = 0; c < 32; c += 8) {
      float4 qv0 = qb[c+0], qv1 = qb[c+1], qv2 = qb[c+2], qv3 = qb[c+3];
      float4 qv4 = qb[c+4], qv5 = qb[c+5], qv6 = qb[c+6], qv7 = qb[c+7];
#define ROW_ONLINE(KR, MR, LR)                                                 \
      {                                                                        \
        float d0 = DOT4(KR, qv0), d1 = DOT4(KR, qv1);                          \
        float d2 = DOT4(KR, qv2), d3 = DOT4(KR, qv3);                          \
        float d4 = DOT4(KR, qv4), d5 = DOT4(KR, qv5);                          \
        float d6 = DOT4(KR, qv6), d7 = DOT4(KR, qv7);                          \
        float cm = fmaxf(fmaxf(fmaxf(d0,d1), fmaxf(d2,d3)),                    \
                         fmaxf(fmaxf(d4,d5), fmaxf(d6,d7)));                   \
        if (cm > MR) { LR *= EXP2(MR - cm); MR = cm; }                         \
        LR += ((EXP2(d0-MR) + EXP2(d1-MR)) + (EXP2(d2-MR) + EXP2(d3-MR)))      \
            + ((EXP2(d4-MR) + EXP2(d5-MR)) + (EXP2(d6-MR) + EXP2(d7-MR)));     \
      }
      ROW_ONLINE(k0, m0, l0)
      ROW_ONLINE(k1, m1, l1)
      ROW_ONLINE(k2, m2, l2)
      ROW_ONLINE(k3, m3, l3)
#undef ROW_ONLINE
    }
    float4* pp4 = reinterpret_cast<float4*>(&Pp[slice * kRows + quad*4]);
    pp4[0] = make_float4(m0, l0, m1, l1);
    pp4[1] = make_float4(m2, l2, m3, l3);
  }
  __syncthreads();

  // ---- merge 16 j-slice partials per row (exact max, scaled sums) ----
  if (tid < kRows) {
    float m = -INFINITY;
    float2 pr[16];
#pragma unroll
    for (int sl = 0; sl < 16; ++sl) {
      pr[sl] = Pp[sl * kRows + tid];
      m = fmaxf(m, pr[sl].x);
    }
    float l = 0.f;
#pragma unroll
    for (int sl = 0; sl < 16; ++sl) l += pr[sl].y * EXP2(pr[sl].x - m);
    Cs[tid] = m + LOG2F(l);            // l in [1,512]
  }
  __syncthreads();

  // ---- phase 3: colsum, register-tiled (R10/R12 proven) ----
  {
    const int cq = tid & 127;
    const int rs = tid >> 7;
    const float4 q0 = Qs[cq*4+0], q1 = Qs[cq*4+1];
    const float4 q2 = Qs[cq*4+2], q3 = Qs[cq*4+3];
    const float4* kb = &Ks[rs << 5];
    const float4* cb = reinterpret_cast<const float4*>(&Cs[rs << 5]);

    float a0=0.f, a1=0.f, a2=0.f, a3=0.f;
#pragma unroll 2
    for (int ii = 0; ii < 8; ++ii) {
      float4 cc = cb[ii];
      float4 ka = kb[ii*4+0], kb_ = kb[ii*4+1], kc = kb[ii*4+2], kd = kb[ii*4+3];
      a0 += EXP2(DOT4A(q0, ka, -cc.x));  a1 += EXP2(DOT4A(q1, ka, -cc.x));
      a2 += EXP2(DOT4A(q2, ka, -cc.x));  a3 += EXP2(DOT4A(q3, ka, -cc.x));
      a0 += EXP2(DOT4A(q0, kb_, -cc.y)); a1 += EXP2(DOT4A(q1, kb_, -cc.y));
      a2 += EXP2(DOT4A(q2, kb_, -cc.y)); a3 += EXP2(DOT4A(q3, kb_, -cc.y));
      a0 += EXP2(DOT4A(q0, kc, -cc.z));  a1 += EXP2(DOT4A(q1, kc, -cc.z));
      a2 += EXP2(DOT4A(q2, kc, -cc.z));  a3 += EXP2(DOT4A(q3, kc, -cc.z));
      a0 += EXP2(DOT4A(q0, kd, -cc.w));  a1 += EXP2(DOT4A(q1, kd, -cc.w));
      a2 += EXP2(DOT4A(q2, kd, -cc.w));  a3 += EXP2(DOT4A(q3, kd, -cc.w));
    }
    reinterpret_cast<float4*>(apart + ((size_t)(tile*4 + s) * 4 + rs) * kN)[cq] =
        make_float4(a0, a1, a2, a3);
  }
}

// ============ KB: sum 16 partials + top-12; grid 128, block 64 ============
__global__ __launch_bounds__(64) void topk_kernel(
    const float* __restrict__ apart, int* __restrict__ out)
{
  const int lane = threadIdx.x;
  const int bt   = blockIdx.x;
  const float* P = apart + (size_t)bt * 16 * kN;

  float v[8];
  {
    float4 acc0 = make_float4(0.f,0.f,0.f,0.f);
    float4 acc1 = make_float4(0.f,0.f,0.f,0.f);
#pragma unroll
    for (int sl = 0; sl < 16; ++sl) {
      const float4* Ps = reinterpret_cast<const float4*>(P + sl * kN);
      float4 u0 = Ps[lane*2], u1 = Ps[lane*2+1];
      acc0.x += u0.x; acc0.y += u0.y; acc0.z += u0.z; acc0.w += u0.w;
      acc1.x += u1.x; acc1.y += u1.y; acc1.z += u1.z; acc1.w += u1.w;
    }
    v[0]=acc0.x; v[1]=acc0.y; v[2]=acc0.z; v[3]=acc0.w;
    v[4]=acc1.x; v[5]=acc1.y; v[6]=acc1.z; v[7]=acc1.w;
  }

  for (int rnd = 0; rnd < kTopK; ++rnd) {
    float bv = v[0];
    int   bi = lane * 8;
#pragma unroll
    for (int r = 1; r < 8; ++r) {
      if (v[r] > bv) { bv = v[r]; bi = lane * 8 + r; }
    }
#pragma unroll
    for (int off = 32; off >= 1; off >>= 1) {
      float ov = __shfl_xor(bv, off);
      int   oi = __shfl_xor(bi, off);
      if (ov > bv || (ov == bv && oi < bi)) { bv = ov; bi = oi; }
    }
    if (lane == 0) out[bt * kTopK + rnd] = bi;
#pragma unroll
    for (int r = 0; r < 8; ++r) {
      if (lane * 8 + r == bi) v[r] = -INFINITY;
    }
  }
}

// ============ fallback: round-1 single kernel (unexpected shape / tiny ws) ============
__global__ __launch_bounds__(512, 1) void sparse_attn_topk_fallback(
    const float* __restrict__ x, const float* __restrict__ flat, int* __restrict__ out)
{
  __shared__ float4 wk4[kDIn];
  __shared__ float4 wq4[kDIn];
  __shared__ float4 Ks[kN];
  __shared__ float4 Qs[kN];
  __shared__ float  Ms[kN];
  __shared__ float  Rl[kN];
  __shared__ float  As[kN];

  const int tid = threadIdx.x;
  const int bt  = blockIdx.x;

  if (tid < 64)       wk4[tid]      = reinterpret_cast<const float4*>(flat)[tid];
  else if (tid < 128) wq4[tid - 64] = reinterpret_cast<const float4*>(flat)[tid];
  __syncthreads();

  const float* xr = x + ((size_t)bt * kN + tid) * kDIn;
  float k0=0.f,k1=0.f,k2=0.f,k3=0.f, q0=0.f,q1=0.f,q2=0.f,q3=0.f;
#pragma unroll
  for (int c = 0; c < kDIn; ++c) {
    float xv = xr[c];
    float4 a = wk4[c];
    float4 b = wq4[c];
    k0 = fmaf(xv, a.x, k0); k1 = fmaf(xv, a.y, k1);
    k2 = fmaf(xv, a.z, k2); k3 = fmaf(xv, a.w, k3);
    q0 = fmaf(xv, b.x, q0); q1 = fmaf(xv, b.y, q1);
    q2 = fmaf(xv, b.z, q2); q3 = fmaf(xv, b.w, q3);
  }
  Ks[tid] = make_float4(k0, k1, k2, k3);
  Qs[tid] = make_float4(q0, q1, q2, q3);
  __syncthreads();

  float m = -INFINITY;
#pragma unroll 8
  for (int j = 0; j < kN; ++j) {
    float4 qj = Qs[j];
    float h = fmaf(k0, qj.x, fmaf(k1, qj.y, fmaf(k2, qj.z, k3 * qj.w)));
    m = fmaxf(m, h);
  }
  float l = 0.f;
#pragma unroll 8
  for (int j = 0; j < kN; ++j) {
    float4 qj = Qs[j];
    float h = fmaf(k0, qj.x, fmaf(k1, qj.y, fmaf(k2, qj.z, k3 * qj.w)));
    l += exp2f(CEXP * (h - m));
  }
  Ms[tid] = m;
  Rl[tid] = 1.0f / l;
  __syncthreads();

  float acc = 0.f;
#pragma unroll 8
  for (int i = 0; i < kN; ++i) {
    float4 ki = Ks[i];
    float h = fmaf(q0, ki.x, fmaf(q1, ki.y, fmaf(q2, ki.z, q3 * ki.w)));
    acc += exp2f(CEXP * (h - Ms[i])) * Rl[i];
  }
  As[tid] = acc;
  __syncthreads();

  if (tid < 64) {
    float v[8];
#pragma unroll
    for (int r = 0; r < 8; ++r) v[r] = As[tid * 8 + r];
    for (int rnd = 0; rnd < kTopK; ++rnd) {
      float bv = v[0];
      int   bi = tid * 8;
#pragma unroll
      for (int r = 1; r < 8; ++r)
        if (v[r] > bv) { bv = v[r]; bi = tid * 8 + r; }
#pragma unroll
      for (int off = 32; off >= 1; off >>= 1) {
        float ov = __shfl_xor(bv, off);
        int   oi = __shfl_xor(bi, off);
        if (ov > bv || (ov == bv && oi < bi)) { bv = ov; bi = oi; }
      }
      if (tid == 0) out[bt * kTopK + rnd] = bi;
#pragma unroll
      for (int r = 0; r < 8; ++r)
        if (tid * 8 + r == bi) v[r] = -INFINITY;
    }
  }
}

extern "C" void kernel_launch(void* const* d_in, const int* in_sizes, int n_in,
                              void* d_out, int out_size, void* d_ws, size_t ws_size,
                              hipStream_t stream) {
  const float* x    = (const float*)d_in[0];
  const float* flat = (const float*)d_in[1];
  int* out = (int*)d_out;
  const int n_bt = in_sizes[0] / (kN * kDIn);

  if (n_bt != kNBt || ws_size < kWsFloats * sizeof(float)) {
    sparse_attn_topk_fallback<<<n_bt, kN, 0, stream>>>(x, flat, out);
    return;
  }
  float* apart = (float*)d_ws;
  fused_attn_kernel<<<kNBt * kS, 512, 0, stream>>>(x, flat, apart);
  topk_kernel      <<<kNBt,       64, 0, stream>>>(apart, out);
}